// Round 16
// baseline (172.328 us; speedup 1.0000x reference)
//
#include <hip/hip_runtime.h>
#include <hip/hip_bf16.h>

// Problem constants
#define E_DIM 1024
#define T_DIM 2048
#define B_DIM 2
#define H_DIM 16
#define HD_DIM 64
#define R_DIM 8
#define M_ROWS (T_DIM * B_DIM)   // 4096 rows for all projections
#define LOG2E 1.4426950408889634f

typedef __attribute__((ext_vector_type(8))) short bf16x8;   // 8 bf16 (4 VGPRs)
typedef __attribute__((ext_vector_type(4))) short bf16x4;   // 4 bf16 (2 VGPRs)
typedef __attribute__((ext_vector_type(4))) float f32x4;    // 4 fp32 acc
typedef __attribute__((ext_vector_type(2))) unsigned uint2v;

#if __has_builtin(__builtin_amdgcn_exp2f)
#define EXP2F(x) __builtin_amdgcn_exp2f(x)
#else
#define EXP2F(x) exp2f(x)
#endif

// round-to-nearest-even f32 -> bf16 (as raw ushort)
__device__ __forceinline__ unsigned short f2bf(float f) {
  unsigned int u = __builtin_bit_cast(unsigned int, f);
  u += 0x7FFFu + ((u >> 16) & 1u);
  return (unsigned short)(u >> 16);
}

// packed f32x2 -> bf16x2 (RNE), src0 -> low16 (HW-verified rounds 5/6/9/10)
__device__ __forceinline__ unsigned cvt_pk_bf16(float lo, float hi) {
  unsigned r;
  asm("v_cvt_pk_bf16_f32 %0, %1, %2" : "=v"(r) : "v"(lo), "v"(hi));
  return r;
}

// K=16 bf16 MFMA (A,B = 4 bf16 / 2 VGPRs each) — HW-verified rounds 10-15.
__device__ __forceinline__ f32x4 mfma16(bf16x4 a, bf16x4 b, f32x4 c) {
#if __has_builtin(__builtin_amdgcn_mfma_f32_16x16x16bf16_1k)
  return __builtin_amdgcn_mfma_f32_16x16x16bf16_1k(a, b, c, 0, 0, 0);
#elif __has_builtin(__builtin_amdgcn_mfma_f32_16x16x16_bf16)
  return __builtin_amdgcn_mfma_f32_16x16x16_bf16(a, b, c, 0, 0, 0);
#else
  asm("v_mfma_f32_16x16x16_bf16 %0, %1, %2, %0" : "+v"(c) : "v"(a), "v"(b));
  return c;
#endif
}

// async global -> LDS, 16B per lane (dest must be wave-uniform base + lane*16)
__device__ __forceinline__ void glds16(const unsigned short* g, unsigned short* l) {
  __builtin_amdgcn_global_load_lds(
      (__attribute__((address_space(1))) void*)(g),
      (__attribute__((address_space(3))) void*)(l), 16, 0, 0);
}

// ---------------------------------------------------------------------------
// prep: fused f32->bf16 converts (query, k_w, out_w) + DoRA pass1
// grid: 6656 blocks of 256. Blocks [0,6144): converts; [6144,6656): dora.
// ---------------------------------------------------------------------------
__global__ __launch_bounds__(256) void prep(
    const float* __restrict__ query, const float* __restrict__ k_w,
    const float* __restrict__ out_w,
    const float* __restrict__ dir_q, const float* __restrict__ A_q, const float* __restrict__ B_q,
    const float* __restrict__ dir_v, const float* __restrict__ A_v, const float* __restrict__ B_v,
    unsigned short* __restrict__ qA_bf, unsigned short* __restrict__ kw_bf,
    unsigned short* __restrict__ ow_bf,
    unsigned short* __restrict__ Wq, unsigned short* __restrict__ Wv,
    float* __restrict__ partials) {
  const int bid = blockIdx.x;
  if (bid < 6144) {
    int u = bid * 256 + threadIdx.x;     // float4 units, total exactly 1572864
    const float* src;
    unsigned short* dst;
    if (u < 1048576) { src = query; dst = qA_bf; }
    else if (u < 1310720) { src = k_w; dst = kw_bf; u -= 1048576; }
    else { src = out_w; dst = ow_bf; u -= 1310720; }
    float4 f = reinterpret_cast<const float4*>(src)[u];
    ushort4 o;
    o.x = f2bf(f.x); o.y = f2bf(f.y); o.z = f2bf(f.z); o.w = f2bf(f.w);
    reinterpret_cast<ushort4*>(dst)[u] = o;
    return;
  }
  // DoRA pass1: Vu = dir + B@A -> bf16 W, fp32 partial sums of Vu^2
  const int bid2 = bid - 6144;
  const int mat = bid2 >> 8, bx = bid2 & 255;
  const float* __restrict__ dir = mat ? dir_v : dir_q;
  const float* __restrict__ Am  = mat ? A_v   : A_q;
  const float* __restrict__ Bm  = mat ? B_v   : B_q;
  unsigned short* __restrict__ W = mat ? Wv : Wq;

  float sum = 0.0f;
  for (int idx = bx * 256 + threadIdx.x; idx < E_DIM * E_DIM; idx += 256 * 256) {
    int i = idx >> 10;
    int j = idx & (E_DIM - 1);
    float v = dir[idx];
#pragma unroll
    for (int r = 0; r < R_DIM; ++r)
      v += Bm[i * R_DIM + r] * Am[r * E_DIM + j];
    W[idx] = f2bf(v);
    sum += v * v;          // norm on fp32 values (matches reference)
  }
#pragma unroll
  for (int off = 32; off > 0; off >>= 1) sum += __shfl_down(sum, off);
  __shared__ float red[4];
  if ((threadIdx.x & 63) == 0) red[threadIdx.x >> 6] = sum;
  __syncthreads();
  if (threadIdx.x == 0)
    partials[mat * 256 + bx] = (red[0] + red[1]) + (red[2] + red[3]);
}

// ---------------------------------------------------------------------------
// Fused Q+K+V^T projections: grid 384, XCD-swizzled (384 % 8 == 0).
// swz [0,256): FUSED q+k block — q,k share the staged A-panel (x rows).
// swz [256,384): FUSED V^T-pair block — two x-panels share the staged Wv
// panel (A-operand); 3 staged tiles -> 2 output tiles, 32 MFMA/barrier-pair.
// DoRA scale reduction folded in (deterministic tree).
// ---------------------------------------------------------------------------
__global__ __launch_bounds__(256, 2) void gemm_qkv(
    const unsigned short* __restrict__ Abf,
    const unsigned short* __restrict__ Wq, const unsigned short* __restrict__ Wk,
    const unsigned short* __restrict__ Wv,
    const float* __restrict__ bias_q, const float* __restrict__ k_b,
    const float* __restrict__ bias_v,
    const float* __restrict__ partials, const float* __restrict__ mag_q,
    const float* __restrict__ mag_v,
    unsigned short* __restrict__ qbuf, unsigned short* __restrict__ kbuf,
    unsigned short* __restrict__ vT) {
  const int bid = blockIdx.x;
  const int swz = (bid & 7) * 48 + (bid >> 3);
  const int tid = threadIdx.x;
  const int w = tid >> 6, lane = tid & 63;
  const int lr = lane & 15, lg = lane >> 4;
  const int wm = w >> 1, wn = w & 1;

  // proven staging decomposition: unit c -> row c>>2, col off (c&3)*8
  const int c0u = tid, c1u = 256 + tid;
  const int r0 = c0u >> 2, o0 = (c0u & 3) * 8;
  const int r1 = c1u >> 2, o1 = (c1u & 3) * 8;

  if (swz >= 256) {
    // ---- fused V^T-pair block: A = Wv[bmv] shared; B = x[bn0], x[bn0+128] ----
    float s = partials[256 + tid];
#pragma unroll
    for (int off = 32; off > 0; off >>= 1) s += __shfl_down(s, off);
    __shared__ float redv[4];
    if ((tid & 63) == 0) redv[tid >> 6] = s;
    __syncthreads();
    float tot = (redv[0] + redv[1]) + (redv[2] + redv[3]);
    const float scale = mag_v[0] / (sqrtf(tot) + 1e-8f);
    __syncthreads();

    const int idx = swz - 256;            // 0..127
    const int bmv = (idx >> 4) * 128;     // Wv row tile (8)
    const int bn0 = (idx & 15) * 256;     // x row pair base (16)

    __shared__ unsigned short As[128 * 32];
    __shared__ unsigned short B0s[128 * 32];
    __shared__ unsigned short B1s[128 * 32];

    f32x4 acc0[4][4], acc1[4][4];
#pragma unroll
    for (int i = 0; i < 4; ++i)
#pragma unroll
      for (int j = 0; j < 4; ++j) {
        acc0[i][j] = (f32x4){0.f, 0.f, 0.f, 0.f};
        acc1[i][j] = (f32x4){0.f, 0.f, 0.f, 0.f};
      }

    for (int k0 = 0; k0 < E_DIM; k0 += 32) {
      glds16(Wv  + (size_t)(bmv + r0) * E_DIM + k0 + o0, As + c0u * 8);
      glds16(Wv  + (size_t)(bmv + r1) * E_DIM + k0 + o1, As + c1u * 8);
      glds16(Abf + (size_t)(bn0 + r0) * E_DIM + k0 + o0, B0s + c0u * 8);
      glds16(Abf + (size_t)(bn0 + r1) * E_DIM + k0 + o1, B0s + c1u * 8);
      glds16(Abf + (size_t)(bn0 + 128 + r0) * E_DIM + k0 + o0, B1s + c0u * 8);
      glds16(Abf + (size_t)(bn0 + 128 + r1) * E_DIM + k0 + o1, B1s + c1u * 8);
      __syncthreads();   // compiler drains vmcnt(0) before barrier

      bf16x8 af[4], b0[4], b1[4];
#pragma unroll
      for (int i = 0; i < 4; ++i)
        af[i] = *reinterpret_cast<const bf16x8*>(As + (wm * 64 + i * 16 + lr) * 32 + lg * 8);
#pragma unroll
      for (int j = 0; j < 4; ++j) {
        b0[j] = *reinterpret_cast<const bf16x8*>(B0s + (wn * 64 + j * 16 + lr) * 32 + lg * 8);
        b1[j] = *reinterpret_cast<const bf16x8*>(B1s + (wn * 64 + j * 16 + lr) * 32 + lg * 8);
      }
#pragma unroll
      for (int i = 0; i < 4; ++i)
#pragma unroll
        for (int j = 0; j < 4; ++j) {
          acc0[i][j] = __builtin_amdgcn_mfma_f32_16x16x32_bf16(af[i], b0[j], acc0[i][j], 0, 0, 0);
          acc1[i][j] = __builtin_amdgcn_mfma_f32_16x16x32_bf16(af[i], b1[j], acc1[i][j], 0, 0, 0);
        }
      __syncthreads();   // all reads done before next stage overwrites
    }

    // proven OUT_MODE-2 scatter, run for both output tiles
#pragma unroll
    for (int p = 0; p < 2; ++p) {
      const int bnp = bn0 + p * 128;
#pragma unroll
      for (int i = 0; i < 4; ++i) {
        int rowbase = bmv + wm * 64 + i * 16 + lg * 4;
        float4 bb = *reinterpret_cast<const float4*>(&bias_v[rowbase]);
        float bbv[4] = {bb.x, bb.y, bb.z, bb.w};
#pragma unroll
        for (int j = 0; j < 4; ++j) {
          int xrow = bnp + wn * 64 + j * 16 + lr;
          int t = xrow >> 1, bsel = xrow & 1;
#pragma unroll
          for (int rr = 0; rr < 4; ++rr) {
            int wrow = rowbase + rr;
            float v = scale * (p ? acc1[i][j][rr] : acc0[i][j][rr]) + bbv[rr];
            int nn = (bsel << 4) | (wrow >> 6);
            int d = wrow & 63;
            vT[((size_t)nn * HD_DIM + d) * T_DIM + t] = f2bf(v);
          }
        }
      }
    }
    return;
  }

  // ---- fused q+k block (proven round 15) ----
  float s = partials[tid];
#pragma unroll
  for (int off = 32; off > 0; off >>= 1) s += __shfl_down(s, off);
  __shared__ float red[4];
  if ((tid & 63) == 0) red[tid >> 6] = s;
  __syncthreads();
  float tot = (red[0] + red[1]) + (red[2] + red[3]);
  const float sm = 0.125f * LOG2E;   // softmax scale * log2(e), folded into q
  const float qscale = (mag_q[0] / (sqrtf(tot) + 1e-8f)) * sm;
  __syncthreads();

  const int bm = (swz >> 3) * 128, bn = (swz & 7) * 128;
  __shared__ unsigned short As[128 * 32];
  __shared__ unsigned short Bqs[128 * 32];
  __shared__ unsigned short Bks[128 * 32];

  f32x4 accq[4][4], acck[4][4];
#pragma unroll
  for (int i = 0; i < 4; ++i)
#pragma unroll
    for (int j = 0; j < 4; ++j) {
      accq[i][j] = (f32x4){0.f, 0.f, 0.f, 0.f};
      acck[i][j] = (f32x4){0.f, 0.f, 0.f, 0.f};
    }

  for (int k0 = 0; k0 < E_DIM; k0 += 32) {
    glds16(Abf + (size_t)(bm + r0) * E_DIM + k0 + o0, As + c0u * 8);
    glds16(Abf + (size_t)(bm + r1) * E_DIM + k0 + o1, As + c1u * 8);
    glds16(Wq + (size_t)(bn + r0) * E_DIM + k0 + o0, Bqs + c0u * 8);
    glds16(Wq + (size_t)(bn + r1) * E_DIM + k0 + o1, Bqs + c1u * 8);
    glds16(Wk + (size_t)(bn + r0) * E_DIM + k0 + o0, Bks + c0u * 8);
    glds16(Wk + (size_t)(bn + r1) * E_DIM + k0 + o1, Bks + c1u * 8);
    __syncthreads();   // compiler drains vmcnt(0) before barrier

    bf16x8 af[4], bq[4], bk[4];
#pragma unroll
    for (int i = 0; i < 4; ++i)
      af[i] = *reinterpret_cast<const bf16x8*>(As + (wm * 64 + i * 16 + lr) * 32 + lg * 8);
#pragma unroll
    for (int j = 0; j < 4; ++j) {
      bq[j] = *reinterpret_cast<const bf16x8*>(Bqs + (wn * 64 + j * 16 + lr) * 32 + lg * 8);
      bk[j] = *reinterpret_cast<const bf16x8*>(Bks + (wn * 64 + j * 16 + lr) * 32 + lg * 8);
    }
#pragma unroll
    for (int i = 0; i < 4; ++i)
#pragma unroll
      for (int j = 0; j < 4; ++j) {
        accq[i][j] = __builtin_amdgcn_mfma_f32_16x16x32_bf16(af[i], bq[j], accq[i][j], 0, 0, 0);
        acck[i][j] = __builtin_amdgcn_mfma_f32_16x16x32_bf16(af[i], bk[j], acck[i][j], 0, 0, 0);
      }
    __syncthreads();   // all reads done before next stage overwrites
  }

  // epilogue: q (scaled) and k outputs
#pragma unroll
  for (int i = 0; i < 4; ++i) {
    int row = bm + wm * 64 + i * 16 + lg * 4;
#pragma unroll
    for (int j = 0; j < 4; ++j) {
      int col = bn + wn * 64 + j * 16 + lr;
      float bq_ = bias_q[col] * sm;
      float bk_ = k_b[col];
#pragma unroll
      for (int r = 0; r < 4; ++r) {
        qbuf[(size_t)(row + r) * E_DIM + col] = f2bf(qscale * accq[i][j][r] + bq_);
        kbuf[(size_t)(row + r) * E_DIM + col] = f2bf(acck[i][j][r] + bk_);
      }
    }
  }
}

// ---------------------------------------------------------------------------
// Output projection: bf16 in, f32 out; grid 256, XCD-swizzled. 1 block/CU ->
// reg-prefetch double-buffer + KBLK=64 double-stage (two BK=32 LDS buffer
// pairs per barrier pair; halves barrier events; R13's lever applied here).
// ---------------------------------------------------------------------------
__global__ __launch_bounds__(256) void gemm_out(
    const unsigned short* __restrict__ Abf, const unsigned short* __restrict__ Wo,
    const float* __restrict__ bias, float* __restrict__ out) {
  const int bid = blockIdx.x;
  const int swz = (bid & 7) * 32 + (bid >> 3);
  const int bm = (swz >> 3) * 128, bn = (swz & 7) * 128;

  __shared__ unsigned short As[2][128 * 32];
  __shared__ unsigned short Bs[2][128 * 32];
  const int tid = threadIdx.x;
  const int w = tid >> 6, lane = tid & 63;
  const int lr = lane & 15, lg = lane >> 4;
  const int wm = w >> 1, wn = w & 1;

  f32x4 acc[4][4];
#pragma unroll
  for (int i = 0; i < 4; ++i)
#pragma unroll
    for (int j = 0; j < 4; ++j) acc[i][j] = (f32x4){0.f, 0.f, 0.f, 0.f};

  const int c0u = tid, c1u = 256 + tid;
  const int r0 = c0u >> 2, o0 = (c0u & 3) * 8;
  const int r1 = c1u >> 2, o1 = (c1u & 3) * 8;

  float4 ra[2][2], rb[2][2];   // [half h][unit]
#pragma unroll
  for (int h = 0; h < 2; ++h) {
    int kk = h * 32;
    ra[h][0] = *reinterpret_cast<const float4*>(Abf + (size_t)(bm + r0) * E_DIM + kk + o0);
    ra[h][1] = *reinterpret_cast<const float4*>(Abf + (size_t)(bm + r1) * E_DIM + kk + o1);
    rb[h][0] = *reinterpret_cast<const float4*>(Wo + (size_t)(bn + r0) * E_DIM + kk + o0);
    rb[h][1] = *reinterpret_cast<const float4*>(Wo + (size_t)(bn + r1) * E_DIM + kk + o1);
  }

  for (int k0 = 0; k0 < E_DIM; k0 += 64) {
    __syncthreads();   // previous tiles' frag reads complete
#pragma unroll
    for (int h = 0; h < 2; ++h) {
      *reinterpret_cast<float4*>(As[h] + c0u * 8) = ra[h][0];
      *reinterpret_cast<float4*>(As[h] + c1u * 8) = ra[h][1];
      *reinterpret_cast<float4*>(Bs[h] + c0u * 8) = rb[h][0];
      *reinterpret_cast<float4*>(Bs[h] + c1u * 8) = rb[h][1];
    }
    __syncthreads();
    if (k0 + 64 < E_DIM) {   // prefetch next 64-K into regs (drains under MFMA)
#pragma unroll
      for (int h = 0; h < 2; ++h) {
        int kk = k0 + 64 + h * 32;
        ra[h][0] = *reinterpret_cast<const float4*>(Abf + (size_t)(bm + r0) * E_DIM + kk + o0);
        ra[h][1] = *reinterpret_cast<const float4*>(Abf + (size_t)(bm + r1) * E_DIM + kk + o1);
        rb[h][0] = *reinterpret_cast<const float4*>(Wo + (size_t)(bn + r0) * E_DIM + kk + o0);
        rb[h][1] = *reinterpret_cast<const float4*>(Wo + (size_t)(bn + r1) * E_DIM + kk + o1);
      }
    }

#pragma unroll
    for (int h = 0; h < 2; ++h) {
      bf16x8 af[4], bf[4];
#pragma unroll
      for (int i = 0; i < 4; ++i)
        af[i] = *reinterpret_cast<const bf16x8*>(As[h] + (wm * 64 + i * 16 + lr) * 32 + lg * 8);
#pragma unroll
      for (int j = 0; j < 4; ++j)
        bf[j] = *reinterpret_cast<const bf16x8*>(Bs[h] + (wn * 64 + j * 16 + lr) * 32 + lg * 8);
#pragma unroll
      for (int i = 0; i < 4; ++i)
#pragma unroll
        for (int j = 0; j < 4; ++j)
          acc[i][j] = __builtin_amdgcn_mfma_f32_16x16x32_bf16(af[i], bf[j], acc[i][j], 0, 0, 0);
    }
  }

  // epilogue: f32 C[row][col] + bias
#pragma unroll
  for (int i = 0; i < 4; ++i) {
    int row = bm + wm * 64 + i * 16 + lg * 4;
#pragma unroll
    for (int j = 0; j < 4; ++j) {
      int col = bn + wn * 64 + j * 16 + lr;
      float bv = bias[col];
#pragma unroll
      for (int r = 0; r < 4; ++r)
        out[(size_t)(row + r) * E_DIM + col] = acc[i][j][r] + bv;
    }
  }
}

// ---------------------------------------------------------------------------
// Flash attention, bf16 MFMA — round-13 proven body (KVBLK=128, swapped QK^T,
// x16 in-lane PV, exp2 softmax, defer-max, shfl_xor reduces), grid (B*H,
// T/256) so a head's 8 q-tile blocks share one XCD (K/V = L2 hits; FETCH
// 12 MB measured round 14). 8 waves x 32 q-rows = 256 rows/block, 1 block/CU.
// ---------------------------------------------------------------------------
#define LDPK 72
#define LDPV 136

__global__ __launch_bounds__(512, 2) void attn_mfma(
    const unsigned short* __restrict__ qb, const unsigned short* __restrict__ kb,
    const unsigned short* __restrict__ vT, unsigned short* __restrict__ ob) {
  __shared__ unsigned short Ks2[128 * LDPK];
  __shared__ unsigned short Vt2[64 * LDPV];
  const int n = blockIdx.x, b = n >> 4, col0 = (n & 15) * HD_DIM;
  const int tid = threadIdx.x, w = tid >> 6, lane = tid & 63;
  const int lr = lane & 15, lg = lane >> 4;
  const int q0 = blockIdx.y * 256 + w * 32;

  // Q fragments, resident whole kernel (B-operand of swapped QK^T)
  bf16x8 qf[2][2];
#pragma unroll
  for (int rf = 0; rf < 2; ++rf)
#pragma unroll
    for (int ks = 0; ks < 2; ++ks)
      qf[rf][ks] = *reinterpret_cast<const bf16x8*>(
          qb + ((size_t)(q0 + rf * 16 + lr) * B_DIM + b) * E_DIM + col0 + ks * 32 + lg * 8);

  f32x4 accO[2][4];
#pragma unroll
  for (int rf = 0; rf < 2; ++rf)
#pragma unroll
    for (int df = 0; df < 4; ++df) accO[rf][df] = (f32x4){0.f, 0.f, 0.f, 0.f};
  float mrun0 = -1e30f, mrun1 = -1e30f, lrun0 = 0.f, lrun1 = 0.f;

  // staging decomposition: 512 threads x 2 float4 units each for K and V.
  const int kr0 = tid >> 3, kc0 = (tid & 7) * 8;
  const int kr1 = 64 + kr0;
  const int vd0 = tid >> 4, vc0 = (tid & 15) * 8;
  const int vd1 = 32 + vd0;
  float4 rk0, rk1, rv0, rv1;
  rk0 = *reinterpret_cast<const float4*>(kb + ((size_t)kr0 * B_DIM + b) * E_DIM + col0 + kc0);
  rk1 = *reinterpret_cast<const float4*>(kb + ((size_t)kr1 * B_DIM + b) * E_DIM + col0 + kc0);
  rv0 = *reinterpret_cast<const float4*>(vT + ((size_t)n * HD_DIM + vd0) * T_DIM + vc0);
  rv1 = *reinterpret_cast<const float4*>(vT + ((size_t)n * HD_DIM + vd1) * T_DIM + vc0);

  for (int kt = 0; kt < T_DIM; kt += 128) {
    __syncthreads();   // all waves done reading previous tiles
    *reinterpret_cast<float4*>(Ks2 + kr0 * LDPK + kc0) = rk0;
    *reinterpret_cast<float4*>(Ks2 + kr1 * LDPK + kc0) = rk1;
    *reinterpret_cast<float4*>(Vt2 + vd0 * LDPV + vc0) = rv0;
    *reinterpret_cast<float4*>(Vt2 + vd1 * LDPV + vc0) = rv1;
    __syncthreads();
    if (kt + 128 < T_DIM) {   // prefetch next 128-key tile into regs
      int kt2 = kt + 128;
      rk0 = *reinterpret_cast<const float4*>(kb + ((size_t)(kt2 + kr0) * B_DIM + b) * E_DIM + col0 + kc0);
      rk1 = *reinterpret_cast<const float4*>(kb + ((size_t)(kt2 + kr1) * B_DIM + b) * E_DIM + col0 + kc0);
      rv0 = *reinterpret_cast<const float4*>(vT + ((size_t)n * HD_DIM + vd0) * T_DIM + kt2 + vc0);
      rv1 = *reinterpret_cast<const float4*>(vT + ((size_t)n * HD_DIM + vd1) * T_DIM + kt2 + vc0);
    }

#pragma unroll
    for (int h = 0; h < 2; ++h) {
      const unsigned short* Kh = Ks2 + h * 64 * LDPK;
      const unsigned short* Vh = Vt2 + h * 64;

      // S^T = K Q^T: lane holds q = q0+rf*16+lr, k = kf*16+lg*4+r (log2e folded)
      f32x4 s[4][2];
#pragma unroll
      for (int kf = 0; kf < 4; ++kf)
#pragma unroll
        for (int rf = 0; rf < 2; ++rf) s[kf][rf] = (f32x4){0.f, 0.f, 0.f, 0.f};
      __builtin_amdgcn_s_setprio(1);
#pragma unroll
      for (int ks = 0; ks < 2; ++ks)
#pragma unroll
        for (int kf = 0; kf < 4; ++kf) {
          bf16x8 kfr = *reinterpret_cast<const bf16x8*>(Kh + (kf * 16 + lr) * LDPK + ks * 32 + lg * 8);
#pragma unroll
          for (int rf = 0; rf < 2; ++rf)
            s[kf][rf] = __builtin_amdgcn_mfma_f32_16x16x32_bf16(kfr, qf[rf][ks], s[kf][rf], 0, 0, 0);
        }
      __builtin_amdgcn_s_setprio(0);

      // row max (tree) + cross-lg reduce (proven shfl_xor path)
      float pm0, pm1;
      {
        float a0 = fmaxf(fmaxf(s[0][0][0], s[0][0][1]), fmaxf(s[0][0][2], s[0][0][3]));
        float a1 = fmaxf(fmaxf(s[1][0][0], s[1][0][1]), fmaxf(s[1][0][2], s[1][0][3]));
        float a2 = fmaxf(fmaxf(s[2][0][0], s[2][0][1]), fmaxf(s[2][0][2], s[2][0][3]));
        float a3 = fmaxf(fmaxf(s[3][0][0], s[3][0][1]), fmaxf(s[3][0][2], s[3][0][3]));
        pm0 = fmaxf(fmaxf(a0, a1), fmaxf(a2, a3));
        float b0 = fmaxf(fmaxf(s[0][1][0], s[0][1][1]), fmaxf(s[0][1][2], s[0][1][3]));
        float b1 = fmaxf(fmaxf(s[1][1][0], s[1][1][1]), fmaxf(s[1][1][2], s[1][1][3]));
        float b2 = fmaxf(fmaxf(s[2][1][0], s[2][1][1]), fmaxf(s[2][1][2], s[2][1][3]));
        float b3 = fmaxf(fmaxf(s[3][1][0], s[3][1][1]), fmaxf(s[3][1][2], s[3][1][3]));
        pm1 = fmaxf(fmaxf(b0, b1), fmaxf(b2, b3));
      }
      pm0 = fmaxf(pm0, __shfl_xor(pm0, 16)); pm0 = fmaxf(pm0, __shfl_xor(pm0, 32));
      pm1 = fmaxf(pm1, __shfl_xor(pm1, 16)); pm1 = fmaxf(pm1, __shfl_xor(pm1, 32));

      // defer-max: skip rescale unless a row's max grew past THR=8 (exp2 dom)
      const int resc = __any((pm0 > mrun0 + 8.0f) || (pm1 > mrun1 + 8.0f));
      float mn0 = mrun0, mn1 = mrun1;
      if (resc) { mn0 = fmaxf(mn0, pm0); mn1 = fmaxf(mn1, pm1); }

      // p = exp2(s - mn) in place
#pragma unroll
      for (int kf = 0; kf < 4; ++kf)
#pragma unroll
        for (int r = 0; r < 4; ++r) {
          s[kf][0][r] = EXP2F(s[kf][0][r] - mn0);
          s[kf][1][r] = EXP2F(s[kf][1][r] - mn1);
        }

      // P -> x16 A-fragments, purely in-lane: pa4[rf][kf] = P[q=lr][k=lg*4+i]
      bf16x4 pa4[2][4];
#pragma unroll
      for (int rf = 0; rf < 2; ++rf)
#pragma unroll
        for (int kf = 0; kf < 4; ++kf) {
          uint2v u = (uint2v){cvt_pk_bf16(s[kf][rf][0], s[kf][rf][1]),
                              cvt_pk_bf16(s[kf][rf][2], s[kf][rf][3])};
          pa4[rf][kf] = __builtin_bit_cast(bf16x4, u);
        }

      // psum (vector tree) + cross-lg reduce
      f32x4 u0 = (s[0][0] + s[1][0]) + (s[2][0] + s[3][0]);
      f32x4 u1 = (s[0][1] + s[1][1]) + (s[2][1] + s[3][1]);
      float ps0 = (u0[0] + u0[1]) + (u0[2] + u0[3]);
      float ps1 = (u1[0] + u1[1]) + (u1[2] + u1[3]);
      ps0 += __shfl_xor(ps0, 16); ps0 += __shfl_xor(ps0, 32);
      ps1 += __shfl_xor(ps1, 16); ps1 += __shfl_xor(ps1, 32);

      if (resc) {
        float al0 = EXP2F(mrun0 - mn0), al1 = EXP2F(mrun1 - mn1);
        mrun0 = mn0; mrun1 = mn1;
        lrun0 = lrun0 * al0 + ps0; lrun1 = lrun1 * al1 + ps1;
#pragma unroll
        for (int r = 0; r < 4; ++r) {
          float a0 = __shfl(al0, (lg << 2) | r);
          float a1 = __shfl(al1, (lg << 2) | r);
#pragma unroll
          for (int df = 0; df < 4; ++df) { accO[0][df][r] *= a0; accO[1][df][r] *= a1; }
        }
      } else {
        lrun0 += ps0; lrun1 += ps1;
      }

      // O += P V via 16x16x16 MFMA: B-frag = V[k=kf*16+lg*4+i][d=df*16+lr]
      __builtin_amdgcn_s_setprio(1);
#pragma unroll
      for (int kf = 0; kf < 4; ++kf) {
#pragma unroll
        for (int df = 0; df < 4; ++df) {
          bf16x4 vf4 = *reinterpret_cast<const bf16x4*>(
              Vh + (df * 16 + lr) * LDPV + kf * 16 + lg * 4);
          accO[0][df] = mfma16(pa4[0][kf], vf4, accO[0][df]);
          accO[1][df] = mfma16(pa4[1][kf], vf4, accO[1][df]);
        }
      }
      __builtin_amdgcn_s_setprio(0);
    }
  }

  // normalize (l broadcast via shfl) + write bf16
#pragma unroll
  for (int rf = 0; rf < 2; ++rf)
#pragma unroll
    for (int r = 0; r < 4; ++r) {
      float lv = __shfl(rf ? lrun1 : lrun0, (lg << 2) | r);
      float inv = 1.0f / lv;
      int row = q0 + rf * 16 + lg * 4 + r;
      size_t base = ((size_t)row * B_DIM + b) * E_DIM + col0;
#pragma unroll
      for (int df = 0; df < 4; ++df)
        ob[base + df * 16 + lr] = f2bf(accO[rf][df][r] * inv);
    }
}

// ---------------------------------------------------------------------------
extern "C" void kernel_launch(void* const* d_in, const int* in_sizes, int n_in,
                              void* d_out, int out_size, void* d_ws, size_t ws_size,
                              hipStream_t stream) {
  const float* query  = (const float*)d_in[0];
  const float* mag_q  = (const float*)d_in[3];
  const float* dir_q  = (const float*)d_in[4];
  const float* A_q    = (const float*)d_in[5];
  const float* B_q    = (const float*)d_in[6];
  const float* bias_q = (const float*)d_in[7];
  const float* mag_v  = (const float*)d_in[8];
  const float* dir_v  = (const float*)d_in[9];
  const float* A_v    = (const float*)d_in[10];
  const float* B_v    = (const float*)d_in[11];
  const float* bias_v = (const float*)d_in[12];
  const float* k_w    = (const float*)d_in[13];
  const float* k_b    = (const float*)d_in[14];
  const float* out_w  = (const float*)d_in[15];
  const float* out_b  = (const float*)d_in[16];
  float* out = (float*)d_out;

  // workspace layout (~48 MB, all regions fully rewritten every call)
  char* ws = (char*)d_ws;
  float* partials = (float*)ws;                          // 2048 B
  unsigned short* qA_bf = (unsigned short*)(ws + 4096);  // query bf16, 8 MB
  unsigned short* wq_bf = qA_bf + (size_t)M_ROWS * E_DIM;
  unsigned short* wv_bf = wq_bf + (size_t)E_DIM * E_DIM;
  unsigned short* kw_bf = wv_bf + (size_t)E_DIM * E_DIM;
  unsigned short* ow_bf = kw_bf + (size_t)E_DIM * E_DIM;
  unsigned short* qbuf  = ow_bf + (size_t)E_DIM * E_DIM;
  unsigned short* kbuf  = qbuf + (size_t)M_ROWS * E_DIM;
  unsigned short* vTbuf = kbuf + (size_t)M_ROWS * E_DIM;  // [b][h][d][t]
  unsigned short* abuf  = vTbuf + (size_t)M_ROWS * E_DIM;

  prep<<<6656, 256, 0, stream>>>(query, k_w, out_w,
                                 dir_q, A_q, B_q, dir_v, A_v, B_v,
                                 qA_bf, kw_bf, ow_bf, wq_bf, wv_bf, partials);

  gemm_qkv<<<384, 256, 0, stream>>>(qA_bf, wq_bf, kw_bf, wv_bf,
                                    bias_q, k_b, bias_v,
                                    partials, mag_q, mag_v,
                                    qbuf, kbuf, vTbuf);
  attn_mfma<<<dim3(B_DIM * H_DIM, T_DIM / 256), 512, 0, stream>>>(
      qbuf, kbuf, vTbuf, abuf);
  gemm_out<<<256, 256, 0, stream>>>(abuf, ow_bf, out_b, out);
}

// Round 17
// 144.730 us; speedup vs baseline: 1.1907x; 1.1907x over previous
//
#include <hip/hip_runtime.h>
#include <hip/hip_bf16.h>

// Problem constants
#define E_DIM 1024
#define T_DIM 2048
#define B_DIM 2
#define H_DIM 16
#define HD_DIM 64
#define R_DIM 8
#define M_ROWS (T_DIM * B_DIM)   // 4096 rows for all projections
#define LOG2E 1.4426950408889634f

typedef __attribute__((ext_vector_type(8))) short bf16x8;   // 8 bf16 (4 VGPRs)
typedef __attribute__((ext_vector_type(4))) short bf16x4;   // 4 bf16 (2 VGPRs)
typedef __attribute__((ext_vector_type(4))) float f32x4;    // 4 fp32 acc
typedef __attribute__((ext_vector_type(2))) unsigned uint2v;

#if __has_builtin(__builtin_amdgcn_exp2f)
#define EXP2F(x) __builtin_amdgcn_exp2f(x)
#else
#define EXP2F(x) exp2f(x)
#endif

// round-to-nearest-even f32 -> bf16 (as raw ushort)
__device__ __forceinline__ unsigned short f2bf(float f) {
  unsigned int u = __builtin_bit_cast(unsigned int, f);
  u += 0x7FFFu + ((u >> 16) & 1u);
  return (unsigned short)(u >> 16);
}

// packed f32x2 -> bf16x2 (RNE), src0 -> low16 (HW-verified rounds 5/6/9/10)
__device__ __forceinline__ unsigned cvt_pk_bf16(float lo, float hi) {
  unsigned r;
  asm("v_cvt_pk_bf16_f32 %0, %1, %2" : "=v"(r) : "v"(lo), "v"(hi));
  return r;
}

// K=16 bf16 MFMA (A,B = 4 bf16 / 2 VGPRs each) — HW-verified rounds 10-15.
__device__ __forceinline__ f32x4 mfma16(bf16x4 a, bf16x4 b, f32x4 c) {
#if __has_builtin(__builtin_amdgcn_mfma_f32_16x16x16bf16_1k)
  return __builtin_amdgcn_mfma_f32_16x16x16bf16_1k(a, b, c, 0, 0, 0);
#elif __has_builtin(__builtin_amdgcn_mfma_f32_16x16x16_bf16)
  return __builtin_amdgcn_mfma_f32_16x16x16_bf16(a, b, c, 0, 0, 0);
#else
  asm("v_mfma_f32_16x16x16_bf16 %0, %1, %2, %0" : "+v"(c) : "v"(a), "v"(b));
  return c;
#endif
}

// async global -> LDS, 16B per lane (dest must be wave-uniform base + lane*16)
__device__ __forceinline__ void glds16(const unsigned short* g, unsigned short* l) {
  __builtin_amdgcn_global_load_lds(
      (__attribute__((address_space(1))) void*)(g),
      (__attribute__((address_space(3))) void*)(l), 16, 0, 0);
}

// ---------------------------------------------------------------------------
// prep: fused f32->bf16 converts (query, k_w, out_w) + DoRA pass1
// grid: 6656 blocks of 256. Blocks [0,6144): converts; [6144,6656): dora.
// ---------------------------------------------------------------------------
__global__ __launch_bounds__(256) void prep(
    const float* __restrict__ query, const float* __restrict__ k_w,
    const float* __restrict__ out_w,
    const float* __restrict__ dir_q, const float* __restrict__ A_q, const float* __restrict__ B_q,
    const float* __restrict__ dir_v, const float* __restrict__ A_v, const float* __restrict__ B_v,
    unsigned short* __restrict__ qA_bf, unsigned short* __restrict__ kw_bf,
    unsigned short* __restrict__ ow_bf,
    unsigned short* __restrict__ Wq, unsigned short* __restrict__ Wv,
    float* __restrict__ partials) {
  const int bid = blockIdx.x;
  if (bid < 6144) {
    int u = bid * 256 + threadIdx.x;     // float4 units, total exactly 1572864
    const float* src;
    unsigned short* dst;
    if (u < 1048576) { src = query; dst = qA_bf; }
    else if (u < 1310720) { src = k_w; dst = kw_bf; u -= 1048576; }
    else { src = out_w; dst = ow_bf; u -= 1310720; }
    float4 f = reinterpret_cast<const float4*>(src)[u];
    ushort4 o;
    o.x = f2bf(f.x); o.y = f2bf(f.y); o.z = f2bf(f.z); o.w = f2bf(f.w);
    reinterpret_cast<ushort4*>(dst)[u] = o;
    return;
  }
  // DoRA pass1: Vu = dir + B@A -> bf16 W, fp32 partial sums of Vu^2
  const int bid2 = bid - 6144;
  const int mat = bid2 >> 8, bx = bid2 & 255;
  const float* __restrict__ dir = mat ? dir_v : dir_q;
  const float* __restrict__ Am  = mat ? A_v   : A_q;
  const float* __restrict__ Bm  = mat ? B_v   : B_q;
  unsigned short* __restrict__ W = mat ? Wv : Wq;

  float sum = 0.0f;
  for (int idx = bx * 256 + threadIdx.x; idx < E_DIM * E_DIM; idx += 256 * 256) {
    int i = idx >> 10;
    int j = idx & (E_DIM - 1);
    float v = dir[idx];
#pragma unroll
    for (int r = 0; r < R_DIM; ++r)
      v += Bm[i * R_DIM + r] * Am[r * E_DIM + j];
    W[idx] = f2bf(v);
    sum += v * v;          // norm on fp32 values (matches reference)
  }
#pragma unroll
  for (int off = 32; off > 0; off >>= 1) sum += __shfl_down(sum, off);
  __shared__ float red[4];
  if ((threadIdx.x & 63) == 0) red[threadIdx.x >> 6] = sum;
  __syncthreads();
  if (threadIdx.x == 0)
    partials[mat * 256 + bx] = (red[0] + red[1]) + (red[2] + red[3]);
}

// ---------------------------------------------------------------------------
// bf16 MFMA GEMM core: C = scale*(A @ W^T) + bscale*bias. 128x128 tile, BK=32,
// 256 thr (4 waves 2x2), 4x4 frags/wave. Staging via global_load_lds width-16.
// OUT_MODE: 1 = bf16 C[row][col];
//           2 = bf16 V^T scatter vT[b][h][d][t], bias indexed by A-row.
// ---------------------------------------------------------------------------
template <int OUT_MODE>
__device__ __forceinline__ void gemm_bt_core(
    const unsigned short* __restrict__ A, const unsigned short* __restrict__ W,
    const float* __restrict__ bias, float scale, float bscale,
    void* __restrict__ Cptr, int bm, int bn) {
  __shared__ unsigned short As[128 * 32];
  __shared__ unsigned short Bs[128 * 32];
  const int tid = threadIdx.x;
  const int w = tid >> 6, lane = tid & 63;
  const int lr = lane & 15, lg = lane >> 4;
  const int wm = w >> 1, wn = w & 1;

  f32x4 acc[4][4];
#pragma unroll
  for (int i = 0; i < 4; ++i)
#pragma unroll
    for (int j = 0; j < 4; ++j) acc[i][j] = (f32x4){0.f, 0.f, 0.f, 0.f};

  // staging decomposition: unit c = it*256+tid -> row r=c>>2, col off=(c&3)*8
  const int c0u = tid, c1u = 256 + tid;
  const int r0 = c0u >> 2, o0 = (c0u & 3) * 8;
  const int r1 = c1u >> 2, o1 = (c1u & 3) * 8;

  for (int k0 = 0; k0 < E_DIM; k0 += 32) {
    glds16(A + (size_t)(bm + r0) * E_DIM + k0 + o0, As + c0u * 8);
    glds16(W + (size_t)(bn + r0) * E_DIM + k0 + o0, Bs + c0u * 8);
    glds16(A + (size_t)(bm + r1) * E_DIM + k0 + o1, As + c1u * 8);
    glds16(W + (size_t)(bn + r1) * E_DIM + k0 + o1, Bs + c1u * 8);
    __syncthreads();   // compiler drains vmcnt(0) before barrier

    bf16x8 af[4], bf[4];
#pragma unroll
    for (int i = 0; i < 4; ++i)
      af[i] = *reinterpret_cast<const bf16x8*>(As + (wm * 64 + i * 16 + lr) * 32 + lg * 8);
#pragma unroll
    for (int j = 0; j < 4; ++j)
      bf[j] = *reinterpret_cast<const bf16x8*>(Bs + (wn * 64 + j * 16 + lr) * 32 + lg * 8);
#pragma unroll
    for (int i = 0; i < 4; ++i)
#pragma unroll
      for (int j = 0; j < 4; ++j)
        acc[i][j] = __builtin_amdgcn_mfma_f32_16x16x32_bf16(af[i], bf[j], acc[i][j], 0, 0, 0);
    __syncthreads();   // all reads done before next stage overwrites
  }

  if (OUT_MODE == 2) {
    // C^T scatter: A-row = V out-dim (wrow), W-row = token row (xrow).
#pragma unroll
    for (int i = 0; i < 4; ++i) {
      int rowbase = bm + wm * 64 + i * 16 + lg * 4;
      float4 bb = *reinterpret_cast<const float4*>(&bias[rowbase]);
      float bbv[4] = {bb.x, bb.y, bb.z, bb.w};
#pragma unroll
      for (int j = 0; j < 4; ++j) {
        int xrow = bn + wn * 64 + j * 16 + lr;
        int t = xrow >> 1, bsel = xrow & 1;
#pragma unroll
        for (int rr = 0; rr < 4; ++rr) {
          int wrow = rowbase + rr;
          float v = scale * acc[i][j][rr] + bbv[rr];
          int nn = (bsel << 4) | (wrow >> 6);
          int d = wrow & 63;
          reinterpret_cast<unsigned short*>(Cptr)[((size_t)nn * HD_DIM + d) * T_DIM + t] = f2bf(v);
        }
      }
    }
  } else {
#pragma unroll
    for (int i = 0; i < 4; ++i) {
      int row = bm + wm * 64 + i * 16 + lg * 4;
#pragma unroll
      for (int j = 0; j < 4; ++j) {
        int col = bn + wn * 64 + j * 16 + lr;
        float bv = bias[col] * bscale;
#pragma unroll
        for (int r = 0; r < 4; ++r) {
          float v = scale * acc[i][j][r] + bv;
          reinterpret_cast<unsigned short*>(Cptr)[(size_t)(row + r) * E_DIM + col] = f2bf(v);
        }
      }
    }
  }
}

// ---------------------------------------------------------------------------
// Fused Q+K+V^T projections: grid 512, XCD-swizzled (512 % 8 == 0).
// swz [0,256): FUSED q+k block — q and k share the identical A-panel, so one
// block stages A once and both W panels (3 tiles/K-step instead of 2x2),
// doubling MFMA per barrier pair. swz [256,512): V^T blocks (proven core).
// DoRA scale reduction folded in (deterministic tree).
// ---------------------------------------------------------------------------
__global__ __launch_bounds__(256, 2) void gemm_qkv(
    const unsigned short* __restrict__ Abf,
    const unsigned short* __restrict__ Wq, const unsigned short* __restrict__ Wk,
    const unsigned short* __restrict__ Wv,
    const float* __restrict__ bias_q, const float* __restrict__ k_b,
    const float* __restrict__ bias_v,
    const float* __restrict__ partials, const float* __restrict__ mag_q,
    const float* __restrict__ mag_v,
    unsigned short* __restrict__ qbuf, unsigned short* __restrict__ kbuf,
    unsigned short* __restrict__ vT) {
  const int bid = blockIdx.x;
  const int swz = (bid & 7) * 64 + (bid >> 3);
  const int tid = threadIdx.x;

  if (swz >= 256) {
    // ---- V^T block (proven core, OUT_MODE 2) ----
    float s = partials[256 + tid];
#pragma unroll
    for (int off = 32; off > 0; off >>= 1) s += __shfl_down(s, off);
    __shared__ float redv[4];
    if ((tid & 63) == 0) redv[tid >> 6] = s;
    __syncthreads();
    float tot = (redv[0] + redv[1]) + (redv[2] + redv[3]);
    float scale = mag_v[0] / (sqrtf(tot) + 1e-8f);
    __syncthreads();
    const int idx = swz - 256;
    gemm_bt_core<2>(Wv, Abf, bias_v, scale, 1.0f, vT,
                    (idx >> 5) * 128, (idx & 31) * 128);
    return;
  }

  // ---- fused q+k block ----
  float s = partials[tid];
#pragma unroll
  for (int off = 32; off > 0; off >>= 1) s += __shfl_down(s, off);
  __shared__ float red[4];
  if ((tid & 63) == 0) red[tid >> 6] = s;
  __syncthreads();
  float tot = (red[0] + red[1]) + (red[2] + red[3]);
  const float sm = 0.125f * LOG2E;   // softmax scale * log2(e), folded into q
  const float qscale = (mag_q[0] / (sqrtf(tot) + 1e-8f)) * sm;
  __syncthreads();

  const int bm = (swz >> 3) * 128, bn = (swz & 7) * 128;
  __shared__ unsigned short As[128 * 32];
  __shared__ unsigned short Bqs[128 * 32];
  __shared__ unsigned short Bks[128 * 32];
  const int w = tid >> 6, lane = tid & 63;
  const int lr = lane & 15, lg = lane >> 4;
  const int wm = w >> 1, wn = w & 1;

  f32x4 accq[4][4], acck[4][4];
#pragma unroll
  for (int i = 0; i < 4; ++i)
#pragma unroll
    for (int j = 0; j < 4; ++j) {
      accq[i][j] = (f32x4){0.f, 0.f, 0.f, 0.f};
      acck[i][j] = (f32x4){0.f, 0.f, 0.f, 0.f};
    }

  // proven staging decomposition: unit c -> row c>>2, col off (c&3)*8
  const int c0u = tid, c1u = 256 + tid;
  const int r0 = c0u >> 2, o0 = (c0u & 3) * 8;
  const int r1 = c1u >> 2, o1 = (c1u & 3) * 8;

  for (int k0 = 0; k0 < E_DIM; k0 += 32) {
    glds16(Abf + (size_t)(bm + r0) * E_DIM + k0 + o0, As + c0u * 8);
    glds16(Abf + (size_t)(bm + r1) * E_DIM + k0 + o1, As + c1u * 8);
    glds16(Wq + (size_t)(bn + r0) * E_DIM + k0 + o0, Bqs + c0u * 8);
    glds16(Wq + (size_t)(bn + r1) * E_DIM + k0 + o1, Bqs + c1u * 8);
    glds16(Wk + (size_t)(bn + r0) * E_DIM + k0 + o0, Bks + c0u * 8);
    glds16(Wk + (size_t)(bn + r1) * E_DIM + k0 + o1, Bks + c1u * 8);
    __syncthreads();   // compiler drains vmcnt(0) before barrier

    bf16x8 af[4], bq[4], bk[4];
#pragma unroll
    for (int i = 0; i < 4; ++i)
      af[i] = *reinterpret_cast<const bf16x8*>(As + (wm * 64 + i * 16 + lr) * 32 + lg * 8);
#pragma unroll
    for (int j = 0; j < 4; ++j) {
      bq[j] = *reinterpret_cast<const bf16x8*>(Bqs + (wn * 64 + j * 16 + lr) * 32 + lg * 8);
      bk[j] = *reinterpret_cast<const bf16x8*>(Bks + (wn * 64 + j * 16 + lr) * 32 + lg * 8);
    }
#pragma unroll
    for (int i = 0; i < 4; ++i)
#pragma unroll
      for (int j = 0; j < 4; ++j) {
        accq[i][j] = __builtin_amdgcn_mfma_f32_16x16x32_bf16(af[i], bq[j], accq[i][j], 0, 0, 0);
        acck[i][j] = __builtin_amdgcn_mfma_f32_16x16x32_bf16(af[i], bk[j], acck[i][j], 0, 0, 0);
      }
    __syncthreads();   // all reads done before next stage overwrites
  }

  // epilogue: q (scaled) and k outputs
#pragma unroll
  for (int i = 0; i < 4; ++i) {
    int row = bm + wm * 64 + i * 16 + lg * 4;
#pragma unroll
    for (int j = 0; j < 4; ++j) {
      int col = bn + wn * 64 + j * 16 + lr;
      float bq_ = bias_q[col] * sm;
      float bk_ = k_b[col];
#pragma unroll
      for (int r = 0; r < 4; ++r) {
        qbuf[(size_t)(row + r) * E_DIM + col] = f2bf(qscale * accq[i][j][r] + bq_);
        kbuf[(size_t)(row + r) * E_DIM + col] = f2bf(acck[i][j][r] + bk_);
      }
    }
  }
}

// ---------------------------------------------------------------------------
// Output projection: bf16 in, f32 out; grid 256, XCD-swizzled. 1 block/CU ->
// reg-prefetch double-buffer (next tile's global loads drain under MFMA).
// ---------------------------------------------------------------------------
__global__ __launch_bounds__(256) void gemm_out(
    const unsigned short* __restrict__ Abf, const unsigned short* __restrict__ Wo,
    const float* __restrict__ bias, float* __restrict__ out) {
  const int bid = blockIdx.x;
  const int swz = (bid & 7) * 32 + (bid >> 3);
  const int bm = (swz >> 3) * 128, bn = (swz & 7) * 128;

  __shared__ unsigned short As[128 * 32];
  __shared__ unsigned short Bs[128 * 32];
  const int tid = threadIdx.x;
  const int w = tid >> 6, lane = tid & 63;
  const int lr = lane & 15, lg = lane >> 4;
  const int wm = w >> 1, wn = w & 1;

  f32x4 acc[4][4];
#pragma unroll
  for (int i = 0; i < 4; ++i)
#pragma unroll
    for (int j = 0; j < 4; ++j) acc[i][j] = (f32x4){0.f, 0.f, 0.f, 0.f};

  const int c0u = tid, c1u = 256 + tid;
  const int r0 = c0u >> 2, o0 = (c0u & 3) * 8;
  const int r1 = c1u >> 2, o1 = (c1u & 3) * 8;

  float4 ra0, ra1, rb0, rb1;
  ra0 = *reinterpret_cast<const float4*>(Abf + (size_t)(bm + r0) * E_DIM + o0);
  ra1 = *reinterpret_cast<const float4*>(Abf + (size_t)(bm + r1) * E_DIM + o1);
  rb0 = *reinterpret_cast<const float4*>(Wo + (size_t)(bn + r0) * E_DIM + o0);
  rb1 = *reinterpret_cast<const float4*>(Wo + (size_t)(bn + r1) * E_DIM + o1);

  for (int k0 = 0; k0 < E_DIM; k0 += 32) {
    __syncthreads();   // previous tile's frag reads complete
    *reinterpret_cast<float4*>(As + c0u * 8) = ra0;
    *reinterpret_cast<float4*>(As + c1u * 8) = ra1;
    *reinterpret_cast<float4*>(Bs + c0u * 8) = rb0;
    *reinterpret_cast<float4*>(Bs + c1u * 8) = rb1;
    __syncthreads();
    if (k0 + 32 < E_DIM) {   // prefetch next tile into regs (drains under MFMA)
      ra0 = *reinterpret_cast<const float4*>(Abf + (size_t)(bm + r0) * E_DIM + k0 + 32 + o0);
      ra1 = *reinterpret_cast<const float4*>(Abf + (size_t)(bm + r1) * E_DIM + k0 + 32 + o1);
      rb0 = *reinterpret_cast<const float4*>(Wo + (size_t)(bn + r0) * E_DIM + k0 + 32 + o0);
      rb1 = *reinterpret_cast<const float4*>(Wo + (size_t)(bn + r1) * E_DIM + k0 + 32 + o1);
    }

    bf16x8 af[4], bf[4];
#pragma unroll
    for (int i = 0; i < 4; ++i)
      af[i] = *reinterpret_cast<const bf16x8*>(As + (wm * 64 + i * 16 + lr) * 32 + lg * 8);
#pragma unroll
    for (int j = 0; j < 4; ++j)
      bf[j] = *reinterpret_cast<const bf16x8*>(Bs + (wn * 64 + j * 16 + lr) * 32 + lg * 8);
#pragma unroll
    for (int i = 0; i < 4; ++i)
#pragma unroll
      for (int j = 0; j < 4; ++j)
        acc[i][j] = __builtin_amdgcn_mfma_f32_16x16x32_bf16(af[i], bf[j], acc[i][j], 0, 0, 0);
  }

  // epilogue: f32 C[row][col] + bias
#pragma unroll
  for (int i = 0; i < 4; ++i) {
    int row = bm + wm * 64 + i * 16 + lg * 4;
#pragma unroll
    for (int j = 0; j < 4; ++j) {
      int col = bn + wn * 64 + j * 16 + lr;
      float bv = bias[col];
#pragma unroll
      for (int r = 0; r < 4; ++r)
        out[(size_t)(row + r) * E_DIM + col] = acc[i][j][r] + bv;
    }
  }
}

// ---------------------------------------------------------------------------
// Flash attention, bf16 MFMA — round-13 proven body (KVBLK=128, swapped QK^T,
// x16 in-lane PV, exp2 softmax, defer-max, shfl_xor reduces), grid (B*H,
// T/256) so a head's 8 q-tile blocks share one XCD (K/V = L2 hits; FETCH
// 12 MB measured round 14). 8 waves x 32 q-rows = 256 rows/block, 1 block/CU.
// ---------------------------------------------------------------------------
#define LDPK 72
#define LDPV 136

__global__ __launch_bounds__(512, 2) void attn_mfma(
    const unsigned short* __restrict__ qb, const unsigned short* __restrict__ kb,
    const unsigned short* __restrict__ vT, unsigned short* __restrict__ ob) {
  __shared__ unsigned short Ks2[128 * LDPK];
  __shared__ unsigned short Vt2[64 * LDPV];
  const int n = blockIdx.x, b = n >> 4, col0 = (n & 15) * HD_DIM;
  const int tid = threadIdx.x, w = tid >> 6, lane = tid & 63;
  const int lr = lane & 15, lg = lane >> 4;
  const int q0 = blockIdx.y * 256 + w * 32;

  // Q fragments, resident whole kernel (B-operand of swapped QK^T)
  bf16x8 qf[2][2];
#pragma unroll
  for (int rf = 0; rf < 2; ++rf)
#pragma unroll
    for (int ks = 0; ks < 2; ++ks)
      qf[rf][ks] = *reinterpret_cast<const bf16x8*>(
          qb + ((size_t)(q0 + rf * 16 + lr) * B_DIM + b) * E_DIM + col0 + ks * 32 + lg * 8);

  f32x4 accO[2][4];
#pragma unroll
  for (int rf = 0; rf < 2; ++rf)
#pragma unroll
    for (int df = 0; df < 4; ++df) accO[rf][df] = (f32x4){0.f, 0.f, 0.f, 0.f};
  float mrun0 = -1e30f, mrun1 = -1e30f, lrun0 = 0.f, lrun1 = 0.f;

  // staging decomposition: 512 threads x 2 float4 units each for K and V.
  const int kr0 = tid >> 3, kc0 = (tid & 7) * 8;
  const int kr1 = 64 + kr0;
  const int vd0 = tid >> 4, vc0 = (tid & 15) * 8;
  const int vd1 = 32 + vd0;
  float4 rk0, rk1, rv0, rv1;
  rk0 = *reinterpret_cast<const float4*>(kb + ((size_t)kr0 * B_DIM + b) * E_DIM + col0 + kc0);
  rk1 = *reinterpret_cast<const float4*>(kb + ((size_t)kr1 * B_DIM + b) * E_DIM + col0 + kc0);
  rv0 = *reinterpret_cast<const float4*>(vT + ((size_t)n * HD_DIM + vd0) * T_DIM + vc0);
  rv1 = *reinterpret_cast<const float4*>(vT + ((size_t)n * HD_DIM + vd1) * T_DIM + vc0);

  for (int kt = 0; kt < T_DIM; kt += 128) {
    __syncthreads();   // all waves done reading previous tiles
    *reinterpret_cast<float4*>(Ks2 + kr0 * LDPK + kc0) = rk0;
    *reinterpret_cast<float4*>(Ks2 + kr1 * LDPK + kc0) = rk1;
    *reinterpret_cast<float4*>(Vt2 + vd0 * LDPV + vc0) = rv0;
    *reinterpret_cast<float4*>(Vt2 + vd1 * LDPV + vc0) = rv1;
    __syncthreads();
    if (kt + 128 < T_DIM) {   // prefetch next 128-key tile into regs
      int kt2 = kt + 128;
      rk0 = *reinterpret_cast<const float4*>(kb + ((size_t)(kt2 + kr0) * B_DIM + b) * E_DIM + col0 + kc0);
      rk1 = *reinterpret_cast<const float4*>(kb + ((size_t)(kt2 + kr1) * B_DIM + b) * E_DIM + col0 + kc0);
      rv0 = *reinterpret_cast<const float4*>(vT + ((size_t)n * HD_DIM + vd0) * T_DIM + kt2 + vc0);
      rv1 = *reinterpret_cast<const float4*>(vT + ((size_t)n * HD_DIM + vd1) * T_DIM + kt2 + vc0);
    }

#pragma unroll
    for (int h = 0; h < 2; ++h) {
      const unsigned short* Kh = Ks2 + h * 64 * LDPK;
      const unsigned short* Vh = Vt2 + h * 64;

      // S^T = K Q^T: lane holds q = q0+rf*16+lr, k = kf*16+lg*4+r (log2e folded)
      f32x4 s[4][2];
#pragma unroll
      for (int kf = 0; kf < 4; ++kf)
#pragma unroll
        for (int rf = 0; rf < 2; ++rf) s[kf][rf] = (f32x4){0.f, 0.f, 0.f, 0.f};
      __builtin_amdgcn_s_setprio(1);
#pragma unroll
      for (int ks = 0; ks < 2; ++ks)
#pragma unroll
        for (int kf = 0; kf < 4; ++kf) {
          bf16x8 kfr = *reinterpret_cast<const bf16x8*>(Kh + (kf * 16 + lr) * LDPK + ks * 32 + lg * 8);
#pragma unroll
          for (int rf = 0; rf < 2; ++rf)
            s[kf][rf] = __builtin_amdgcn_mfma_f32_16x16x32_bf16(kfr, qf[rf][ks], s[kf][rf], 0, 0, 0);
        }
      __builtin_amdgcn_s_setprio(0);

      // row max (tree) + cross-lg reduce (proven shfl_xor path)
      float pm0, pm1;
      {
        float a0 = fmaxf(fmaxf(s[0][0][0], s[0][0][1]), fmaxf(s[0][0][2], s[0][0][3]));
        float a1 = fmaxf(fmaxf(s[1][0][0], s[1][0][1]), fmaxf(s[1][0][2], s[1][0][3]));
        float a2 = fmaxf(fmaxf(s[2][0][0], s[2][0][1]), fmaxf(s[2][0][2], s[2][0][3]));
        float a3 = fmaxf(fmaxf(s[3][0][0], s[3][0][1]), fmaxf(s[3][0][2], s[3][0][3]));
        pm0 = fmaxf(fmaxf(a0, a1), fmaxf(a2, a3));
        float b0 = fmaxf(fmaxf(s[0][1][0], s[0][1][1]), fmaxf(s[0][1][2], s[0][1][3]));
        float b1 = fmaxf(fmaxf(s[1][1][0], s[1][1][1]), fmaxf(s[1][1][2], s[1][1][3]));
        float b2 = fmaxf(fmaxf(s[2][1][0], s[2][1][1]), fmaxf(s[2][1][2], s[2][1][3]));
        float b3 = fmaxf(fmaxf(s[3][1][0], s[3][1][1]), fmaxf(s[3][1][2], s[3][1][3]));
        pm1 = fmaxf(fmaxf(b0, b1), fmaxf(b2, b3));
      }
      pm0 = fmaxf(pm0, __shfl_xor(pm0, 16)); pm0 = fmaxf(pm0, __shfl_xor(pm0, 32));
      pm1 = fmaxf(pm1, __shfl_xor(pm1, 16)); pm1 = fmaxf(pm1, __shfl_xor(pm1, 32));

      // defer-max: skip rescale unless a row's max grew past THR=8 (exp2 dom)
      const int resc = __any((pm0 > mrun0 + 8.0f) || (pm1 > mrun1 + 8.0f));
      float mn0 = mrun0, mn1 = mrun1;
      if (resc) { mn0 = fmaxf(mn0, pm0); mn1 = fmaxf(mn1, pm1); }

      // p = exp2(s - mn) in place
#pragma unroll
      for (int kf = 0; kf < 4; ++kf)
#pragma unroll
        for (int r = 0; r < 4; ++r) {
          s[kf][0][r] = EXP2F(s[kf][0][r] - mn0);
          s[kf][1][r] = EXP2F(s[kf][1][r] - mn1);
        }

      // P -> x16 A-fragments, purely in-lane: pa4[rf][kf] = P[q=lr][k=lg*4+i]
      bf16x4 pa4[2][4];
#pragma unroll
      for (int rf = 0; rf < 2; ++rf)
#pragma unroll
        for (int kf = 0; kf < 4; ++kf) {
          uint2v u = (uint2v){cvt_pk_bf16(s[kf][rf][0], s[kf][rf][1]),
                              cvt_pk_bf16(s[kf][rf][2], s[kf][rf][3])};
          pa4[rf][kf] = __builtin_bit_cast(bf16x4, u);
        }

      // psum (vector tree) + cross-lg reduce
      f32x4 u0 = (s[0][0] + s[1][0]) + (s[2][0] + s[3][0]);
      f32x4 u1 = (s[0][1] + s[1][1]) + (s[2][1] + s[3][1]);
      float ps0 = (u0[0] + u0[1]) + (u0[2] + u0[3]);
      float ps1 = (u1[0] + u1[1]) + (u1[2] + u1[3]);
      ps0 += __shfl_xor(ps0, 16); ps0 += __shfl_xor(ps0, 32);
      ps1 += __shfl_xor(ps1, 16); ps1 += __shfl_xor(ps1, 32);

      if (resc) {
        float al0 = EXP2F(mrun0 - mn0), al1 = EXP2F(mrun1 - mn1);
        mrun0 = mn0; mrun1 = mn1;
        lrun0 = lrun0 * al0 + ps0; lrun1 = lrun1 * al1 + ps1;
#pragma unroll
        for (int r = 0; r < 4; ++r) {
          float a0 = __shfl(al0, (lg << 2) | r);
          float a1 = __shfl(al1, (lg << 2) | r);
#pragma unroll
          for (int df = 0; df < 4; ++df) { accO[0][df][r] *= a0; accO[1][df][r] *= a1; }
        }
      } else {
        lrun0 += ps0; lrun1 += ps1;
      }

      // O += P V via 16x16x16 MFMA: B-frag = V[k=kf*16+lg*4+i][d=df*16+lr]
      __builtin_amdgcn_s_setprio(1);
#pragma unroll
      for (int kf = 0; kf < 4; ++kf) {
#pragma unroll
        for (int df = 0; df < 4; ++df) {
          bf16x4 vf4 = *reinterpret_cast<const bf16x4*>(
              Vh + (df * 16 + lr) * LDPV + kf * 16 + lg * 4);
          accO[0][df] = mfma16(pa4[0][kf], vf4, accO[0][df]);
          accO[1][df] = mfma16(pa4[1][kf], vf4, accO[1][df]);
        }
      }
      __builtin_amdgcn_s_setprio(0);
    }
  }

  // normalize (l broadcast via shfl) + write bf16
#pragma unroll
  for (int rf = 0; rf < 2; ++rf)
#pragma unroll
    for (int r = 0; r < 4; ++r) {
      float lv = __shfl(rf ? lrun1 : lrun0, (lg << 2) | r);
      float inv = 1.0f / lv;
      int row = q0 + rf * 16 + lg * 4 + r;
      size_t base = ((size_t)row * B_DIM + b) * E_DIM + col0;
#pragma unroll
      for (int df = 0; df < 4; ++df)
        ob[base + df * 16 + lr] = f2bf(accO[rf][df][r] * inv);
    }
}

// ---------------------------------------------------------------------------
extern "C" void kernel_launch(void* const* d_in, const int* in_sizes, int n_in,
                              void* d_out, int out_size, void* d_ws, size_t ws_size,
                              hipStream_t stream) {
  const float* query  = (const float*)d_in[0];
  const float* mag_q  = (const float*)d_in[3];
  const float* dir_q  = (const float*)d_in[4];
  const float* A_q    = (const float*)d_in[5];
  const float* B_q    = (const float*)d_in[6];
  const float* bias_q = (const float*)d_in[7];
  const float* mag_v  = (const float*)d_in[8];
  const float* dir_v  = (const float*)d_in[9];
  const float* A_v    = (const float*)d_in[10];
  const float* B_v    = (const float*)d_in[11];
  const float* bias_v = (const float*)d_in[12];
  const float* k_w    = (const float*)d_in[13];
  const float* k_b    = (const float*)d_in[14];
  const float* out_w  = (const float*)d_in[15];
  const float* out_b  = (const float*)d_in[16];
  float* out = (float*)d_out;

  // workspace layout (~48 MB, all regions fully rewritten every call)
  char* ws = (char*)d_ws;
  float* partials = (float*)ws;                          // 2048 B
  unsigned short* qA_bf = (unsigned short*)(ws + 4096);  // query bf16, 8 MB
  unsigned short* wq_bf = qA_bf + (size_t)M_ROWS * E_DIM;
  unsigned short* wv_bf = wq_bf + (size_t)E_DIM * E_DIM;
  unsigned short* kw_bf = wv_bf + (size_t)E_DIM * E_DIM;
  unsigned short* ow_bf = kw_bf + (size_t)E_DIM * E_DIM;
  unsigned short* qbuf  = ow_bf + (size_t)E_DIM * E_DIM;
  unsigned short* kbuf  = qbuf + (size_t)M_ROWS * E_DIM;
  unsigned short* vTbuf = kbuf + (size_t)M_ROWS * E_DIM;  // [b][h][d][t]
  unsigned short* abuf  = vTbuf + (size_t)M_ROWS * E_DIM;

  prep<<<6656, 256, 0, stream>>>(query, k_w, out_w,
                                 dir_q, A_q, B_q, dir_v, A_v, B_v,
                                 qA_bf, kw_bf, ow_bf, wq_bf, wv_bf, partials);

  gemm_qkv<<<512, 256, 0, stream>>>(qA_bf, wq_bf, kw_bf, wv_bf,
                                    bias_q, k_b, bias_v,
                                    partials, mag_q, mag_v,
                                    qbuf, kbuf, vTbuf);
  attn_mfma<<<dim3(B_DIM * H_DIM, T_DIM / 256), 512, 0, stream>>>(
      qbuf, kbuf, vTbuf, abuf);
  gemm_out<<<256, 256, 0, stream>>>(abuf, ow_bf, out_b, out);
}